// Round 12
// baseline (77.541 us; speedup 1.0000x reference)
//
#include <hip/hip_runtime.h>
#include <hip/hip_fp16.h>
#include <math.h>

#define B_ 8192
#define P_ 24
#define Q_ 12
#define E_ 256
#define V_ 1000
#define TOK_ 36
#define NI_ 128      // intervals
#define KT_ 8        // intervals per build block
#define NKBLK_ 16    // 128/8
#define NBUILD_ (P_ * NKBLK_)           // 384
#define NCAT_TILES_ (Q_ * (B_ / 16))    // 6144: (q, 16-b chunk)
#define NNUM_TILES_ ((B_ * P_) / 16)    // 12288
#define X0_ (-6.0f)
#define DX_ (12.0f / 128.0f)
#define INVDX_ (128.0f / 12.0f)
#define LN_EPS_ 1e-5f
#define INV_E_ (1.0f / 256.0f)

typedef float vfloat4 __attribute__((ext_vector_type(4)));

__device__ __forceinline__ float gelu_exact(float u) {
    return 0.5f * u * (1.0f + erff(u * 0.70710678118654752f));
}

// Build packed interval table T2[p][i][f] = half2(a, d): a = F_p(x_i)[f],
// d = F_p(x_{i+1})[f] - a. Each block computes 9 knots -> 8 intervals.
__device__ __forceinline__ void do_build_chunk(
        int bid, const float* __restrict__ W1, const float* __restrict__ b1,
        const float* __restrict__ W2, const float* __restrict__ b2,
        __half2* __restrict__ T2, float (*h)[E_ + 4]) {
    int p = bid / NKBLK_;
    int k0 = (bid - p * NKBLK_) * KT_;
    int f = threadIdx.x;

    float w = W1[p * E_ + f];
    float b1v = b1[p * E_ + f];
    #pragma unroll
    for (int k = 0; k < KT_ + 1; ++k) {
        float x = X0_ + (float)(k0 + k) * DX_;
        h[k][f] = gelu_exact(fmaf(x, w, b1v));
    }
    __syncthreads();

    float acc[KT_ + 1];
    float b2v = b2[p * E_ + f];
    #pragma unroll
    for (int k = 0; k < KT_ + 1; ++k) acc[k] = b2v;

    const float* W2p = W2 + (size_t)p * E_ * E_ + f;
    for (int e = 0; e < E_; e += 4) {
        float w0 = W2p[(size_t)(e + 0) * E_];
        float w1 = W2p[(size_t)(e + 1) * E_];
        float w2v = W2p[(size_t)(e + 2) * E_];
        float w3 = W2p[(size_t)(e + 3) * E_];
        #pragma unroll
        for (int k = 0; k < KT_ + 1; ++k) {
            float4 hv = *(const float4*)&h[k][e];
            acc[k] = fmaf(hv.x, w0, acc[k]);
            acc[k] = fmaf(hv.y, w1, acc[k]);
            acc[k] = fmaf(hv.z, w2v, acc[k]);
            acc[k] = fmaf(hv.w, w3, acc[k]);
        }
    }
    #pragma unroll
    for (int k = 0; k < KT_; ++k) {
        int i = k0 + k;
        T2[((size_t)p * NI_ + i) * E_ + f] =
            __floats2half2_rn(acc[k], acc[k + 1] - acc[k]);  // (a, d) packed
    }
}

// LayerNorm one 256-elem row (float4/lane across 64 lanes).
// A/B vs R11: NORMAL store (through L2) instead of nontemporal. Read working
// set is now only ~2.6 MB (packed table + q-major emb slab), so L2 pollution
// risk is gone; testing whether the write-back path has better DRAM efficiency.
__device__ __forceinline__ void ln_store(float4 v, float4 g, float4 bt, int e0, int row,
                                         float* __restrict__ out) {
    float s1 = v.x + v.y + v.z + v.w;
    #pragma unroll
    for (int m = 1; m < 64; m <<= 1) s1 += __shfl_xor(s1, m, 64);
    float mean = s1 * INV_E_;
    float dx = v.x - mean, dy = v.y - mean, dz = v.z - mean, dw = v.w - mean;
    float s2 = dx * dx + dy * dy + dz * dz + dw * dw;
    #pragma unroll
    for (int m = 1; m < 64; m <<= 1) s2 += __shfl_xor(s2, m, 64);
    float rstd = rsqrtf(s2 * INV_E_ + LN_EPS_);
    float4 o;
    o.x = fmaf(dx * rstd, g.x, bt.x);
    o.y = fmaf(dy * rstd, g.y, bt.y);
    o.z = fmaf(dz * rstd, g.z, bt.z);
    o.w = fmaf(dw * rstd, g.w, bt.w);
    *(float4*)&out[(size_t)row * E_ + e0] = o;
}

// q-major cat tile: one q, 16 consecutive b's. 512 consecutive blocks share one
// q -> its 1.02 MB emb slab is L2-resident on every XCD. Wave does 4 b's.
__device__ __forceinline__ void do_cat_tile(
        int ct, int wv, int lane, const int* __restrict__ x_cat,
        const float* __restrict__ emb, float4 g, float4 bt,
        float* __restrict__ out) {
    int q = ct >> 9;                       // ct / 512
    int b0 = (ct & 511) * 16 + wv * 4;     // 4 consecutive b's for this wave
    int e0 = lane * 4;
    const float* eq = emb + (size_t)q * V_ * E_;
    int ids[4];
    #pragma unroll
    for (int j = 0; j < 4; ++j) ids[j] = x_cat[(b0 + j) * Q_ + q];
    float4 v[4];
    #pragma unroll
    for (int j = 0; j < 4; ++j)            // 4 independent gathers in flight
        v[j] = *(const float4*)&eq[(size_t)ids[j] * E_ + e0];
    #pragma unroll
    for (int j = 0; j < 4; ++j)
        ln_store(v[j], g, bt, e0, (b0 + j) * TOK_ + P_ + q, out);
}

// One num tile = 16 consecutive num-rows; this wave does 4. Packed-table path:
// ONE 16B load per row (4 x half2(a,d)) instead of two fp32 loads.
__device__ __forceinline__ void do_num_tile(
        int tile, int wv, int lane, const __half2* __restrict__ T2,
        const float* __restrict__ x_num, float4 g, float4 bt,
        float* __restrict__ out) {
    int r0 = tile * 16 + wv * 4;           // num-row index, mult of 4
    int b = r0 / P_;
    int t0 = r0 - b * P_;                  // mult of 4; 4 rows share b
    int e0 = lane * 4;
    float4 x4 = *(const float4*)&x_num[b * P_ + t0];   // broadcast, 16B-aligned
    float xs[4] = {x4.x, x4.y, x4.z, x4.w};
    const __half2* bases[4];
    float tts[4];
    #pragma unroll
    for (int j = 0; j < 4; ++j) {
        float s = (xs[j] - X0_) * INVDX_;
        float fi = floorf(s);
        fi = fminf(fmaxf(fi, 0.0f), (float)(NI_ - 1));
        tts[j] = s - fi;                   // unclamped -> linear extrapolation
        bases[j] = T2 + ((size_t)(t0 + j) * NI_ + (int)fi) * E_ + e0;
    }
    float4 raw[4];
    #pragma unroll
    for (int j = 0; j < 4; ++j)            // 4 independent 16B loads in flight
        raw[j] = *(const float4*)bases[j];
    int orow = b * TOK_ + t0;
    #pragma unroll
    for (int j = 0; j < 4; ++j) {
        const __half2* hp = (const __half2*)&raw[j];
        float2 p0 = __half22float2(hp[0]);
        float2 p1 = __half22float2(hp[1]);
        float2 p2 = __half22float2(hp[2]);
        float2 p3 = __half22float2(hp[3]);
        float4 v;
        v.x = fmaf(tts[j], p0.y, p0.x);
        v.y = fmaf(tts[j], p1.y, p1.x);
        v.z = fmaf(tts[j], p2.y, p2.x);
        v.w = fmaf(tts[j], p3.y, p3.x);
        ln_store(v, g, bt, e0, orow + j, out);
    }
}

// K1: blocks [0,384) build the packed table; blocks [384,384+6144) do all cat
// tokens q-major. Independent halves overlap; cat hides build latency.
__global__ __launch_bounds__(256) void build_and_cat(
        const float* __restrict__ W1, const float* __restrict__ b1,
        const float* __restrict__ W2, const float* __restrict__ b2,
        const int* __restrict__ x_cat, const float* __restrict__ emb,
        const float* __restrict__ gamma, const float* __restrict__ beta,
        __half2* __restrict__ T2, float* __restrict__ out) {
    __shared__ float h[KT_ + 1][E_ + 4];
    if (blockIdx.x < NBUILD_) {
        do_build_chunk(blockIdx.x, W1, b1, W2, b2, T2, h);
    } else {
        int wv = threadIdx.x >> 6;
        int lane = threadIdx.x & 63;
        int e0 = lane * 4;
        float4 g = *(const float4*)&gamma[e0];
        float4 bt = *(const float4*)&beta[e0];
        do_cat_tile(blockIdx.x - NBUILD_, wv, lane, x_cat, emb, g, bt, out);
    }
}

// K2: all numeric tokens via packed-table interpolation (table L2-hot, 1.6 MB).
__global__ __launch_bounds__(256) void fuse_num(
        const __half2* __restrict__ T2, const float* __restrict__ x_num,
        const float* __restrict__ gamma, const float* __restrict__ beta,
        float* __restrict__ out) {
    int wv = threadIdx.x >> 6;
    int lane = threadIdx.x & 63;
    int e0 = lane * 4;
    float4 g = *(const float4*)&gamma[e0];
    float4 bt = *(const float4*)&beta[e0];
    do_num_tile(blockIdx.x, wv, lane, T2, x_num, g, bt, out);
}

// Exact fallback (no workspace): direct per-row matvec with 64-lane LN.
__global__ __launch_bounds__(256) void fuse_exact(
        const float* __restrict__ x_num, const int* __restrict__ x_cat,
        const float* __restrict__ W1, const float* __restrict__ b1,
        const float* __restrict__ W2, const float* __restrict__ b2,
        const float* __restrict__ emb,
        const float* __restrict__ gamma, const float* __restrict__ beta,
        float* __restrict__ out) {
    int wv = threadIdx.x >> 6;
    int lane = threadIdx.x & 63;
    int row = blockIdx.x * 4 + wv;
    if (row >= B_ * TOK_) return;
    int b = row / TOK_;
    int t = row - b * TOK_;
    int e0 = lane * 4;
    float4 g = *(const float4*)&gamma[e0];
    float4 bt = *(const float4*)&beta[e0];
    float4 v;
    if (t < P_) {
        float x = x_num[b * P_ + t];
        float4 acc = *(const float4*)&b2[t * E_ + e0];
        for (int e = 0; e < E_; ++e) {
            float he = gelu_exact(fmaf(x, W1[t * E_ + e], b1[t * E_ + e]));
            float4 w = *(const float4*)&W2[((size_t)t * E_ + e) * E_ + e0];
            acc.x = fmaf(he, w.x, acc.x);
            acc.y = fmaf(he, w.y, acc.y);
            acc.z = fmaf(he, w.z, acc.z);
            acc.w = fmaf(he, w.w, acc.w);
        }
        v = acc;
    } else {
        int q = t - P_;
        int idx = x_cat[b * Q_ + q];
        v = *(const float4*)&emb[((size_t)q * V_ + idx) * E_ + e0];
    }
    ln_store(v, g, bt, e0, row, out);
}

extern "C" void kernel_launch(void* const* d_in, const int* in_sizes, int n_in,
                              void* d_out, int out_size, void* d_ws, size_t ws_size,
                              hipStream_t stream) {
    const float* x_num = (const float*)d_in[0];
    const int*   x_cat = (const int*)d_in[1];
    const float* W1    = (const float*)d_in[2];
    const float* b1    = (const float*)d_in[3];
    const float* W2    = (const float*)d_in[4];
    const float* b2    = (const float*)d_in[5];
    const float* emb   = (const float*)d_in[6];
    const float* gamma = (const float*)d_in[7];
    const float* beta  = (const float*)d_in[8];
    float* out = (float*)d_out;

    size_t tbl_bytes = (size_t)P_ * NI_ * E_ * sizeof(__half2);   // 1.6 MB

    if (ws_size >= tbl_bytes) {
        __half2* T2 = (__half2*)d_ws;
        build_and_cat<<<NBUILD_ + NCAT_TILES_, 256, 0, stream>>>(
            W1, b1, W2, b2, x_cat, emb, gamma, beta, T2, out);
        fuse_num<<<NNUM_TILES_, 256, 0, stream>>>(T2, x_num, gamma, beta, out);
    } else {
        int nrow_blocks = (B_ * TOK_ + 3) / 4;
        fuse_exact<<<nrow_blocks, 256, 0, stream>>>(x_num, x_cat, W1, b1, W2, b2,
                                                    emb, gamma, beta, out);
    }
}

// Round 13
// 74.364 us; speedup vs baseline: 1.0427x; 1.0427x over previous
//
#include <hip/hip_runtime.h>
#include <hip/hip_fp16.h>
#include <math.h>

#define B_ 8192
#define P_ 24
#define Q_ 12
#define E_ 256
#define V_ 1000
#define TOK_ 36
#define NI_ 128      // intervals
#define KT_ 8        // intervals per build block
#define NKBLK_ 16    // 128/8
#define NBUILD_ (P_ * NKBLK_)           // 384
#define NCAT_TILES_ (Q_ * (B_ / 16))    // 6144: (q, 16-b chunk)
#define NNUM_TILES_ ((B_ * P_) / 16)    // 12288
#define X0_ (-6.0f)
#define DX_ (12.0f / 128.0f)
#define INVDX_ (128.0f / 12.0f)
#define LN_EPS_ 1e-5f
#define INV_E_ (1.0f / 256.0f)

typedef float vfloat4 __attribute__((ext_vector_type(4)));

__device__ __forceinline__ float gelu_exact(float u) {
    return 0.5f * u * (1.0f + erff(u * 0.70710678118654752f));
}

// Build packed interval table T2[p][i][f] = half2(a, d): a = F_p(x_i)[f],
// d = F_p(x_{i+1})[f] - a. Each block computes 9 knots -> 8 intervals.
__device__ __forceinline__ void do_build_chunk(
        int bid, const float* __restrict__ W1, const float* __restrict__ b1,
        const float* __restrict__ W2, const float* __restrict__ b2,
        __half2* __restrict__ T2, float (*h)[E_ + 4]) {
    int p = bid / NKBLK_;
    int k0 = (bid - p * NKBLK_) * KT_;
    int f = threadIdx.x;

    float w = W1[p * E_ + f];
    float b1v = b1[p * E_ + f];
    #pragma unroll
    for (int k = 0; k < KT_ + 1; ++k) {
        float x = X0_ + (float)(k0 + k) * DX_;
        h[k][f] = gelu_exact(fmaf(x, w, b1v));
    }
    __syncthreads();

    float acc[KT_ + 1];
    float b2v = b2[p * E_ + f];
    #pragma unroll
    for (int k = 0; k < KT_ + 1; ++k) acc[k] = b2v;

    const float* W2p = W2 + (size_t)p * E_ * E_ + f;
    for (int e = 0; e < E_; e += 4) {
        float w0 = W2p[(size_t)(e + 0) * E_];
        float w1 = W2p[(size_t)(e + 1) * E_];
        float w2v = W2p[(size_t)(e + 2) * E_];
        float w3 = W2p[(size_t)(e + 3) * E_];
        #pragma unroll
        for (int k = 0; k < KT_ + 1; ++k) {
            float4 hv = *(const float4*)&h[k][e];
            acc[k] = fmaf(hv.x, w0, acc[k]);
            acc[k] = fmaf(hv.y, w1, acc[k]);
            acc[k] = fmaf(hv.z, w2v, acc[k]);
            acc[k] = fmaf(hv.w, w3, acc[k]);
        }
    }
    #pragma unroll
    for (int k = 0; k < KT_; ++k) {
        int i = k0 + k;
        T2[((size_t)p * NI_ + i) * E_ + f] =
            __floats2half2_rn(acc[k], acc[k + 1] - acc[k]);  // (a, d) packed
    }
}

// LayerNorm one 256-elem row (float4/lane across 64 lanes), nontemporal store.
// NT vs normal A/B (R11=74.8 vs R12=77.5 us): NT wins; keep NT.
__device__ __forceinline__ void ln_store(float4 v, float4 g, float4 bt, int e0, int row,
                                         float* __restrict__ out) {
    float s1 = v.x + v.y + v.z + v.w;
    #pragma unroll
    for (int m = 1; m < 64; m <<= 1) s1 += __shfl_xor(s1, m, 64);
    float mean = s1 * INV_E_;
    float dx = v.x - mean, dy = v.y - mean, dz = v.z - mean, dw = v.w - mean;
    float s2 = dx * dx + dy * dy + dz * dz + dw * dw;
    #pragma unroll
    for (int m = 1; m < 64; m <<= 1) s2 += __shfl_xor(s2, m, 64);
    float rstd = rsqrtf(s2 * INV_E_ + LN_EPS_);
    vfloat4 o;
    o.x = fmaf(dx * rstd, g.x, bt.x);
    o.y = fmaf(dy * rstd, g.y, bt.y);
    o.z = fmaf(dz * rstd, g.z, bt.z);
    o.w = fmaf(dw * rstd, g.w, bt.w);
    // out is write-once, never re-read: bypass L2 so table/emb stay resident.
    __builtin_nontemporal_store(o, (vfloat4*)&out[(size_t)row * E_ + e0]);
}

// q-major cat tile: one q, 16 consecutive b's. 512 consecutive blocks share one
// q -> its 1.02 MB emb slab is L2-resident on every XCD. Wave does 4 b's.
__device__ __forceinline__ void do_cat_tile(
        int ct, int wv, int lane, const int* __restrict__ x_cat,
        const float* __restrict__ emb, float4 g, float4 bt,
        float* __restrict__ out) {
    int q = ct >> 9;                       // ct / 512
    int b0 = (ct & 511) * 16 + wv * 4;     // 4 consecutive b's for this wave
    int e0 = lane * 4;
    const float* eq = emb + (size_t)q * V_ * E_;
    int ids[4];
    #pragma unroll
    for (int j = 0; j < 4; ++j) ids[j] = x_cat[(b0 + j) * Q_ + q];
    float4 v[4];
    #pragma unroll
    for (int j = 0; j < 4; ++j)            // 4 independent gathers in flight
        v[j] = *(const float4*)&eq[(size_t)ids[j] * E_ + e0];
    #pragma unroll
    for (int j = 0; j < 4; ++j)
        ln_store(v[j], g, bt, e0, (b0 + j) * TOK_ + P_ + q, out);
}

// One num tile = 16 consecutive num-rows; this wave does 4. Packed-table path:
// ONE 16B load per row (4 x half2(a,d)) instead of two fp32 loads.
__device__ __forceinline__ void do_num_tile(
        int tile, int wv, int lane, const __half2* __restrict__ T2,
        const float* __restrict__ x_num, float4 g, float4 bt,
        float* __restrict__ out) {
    int r0 = tile * 16 + wv * 4;           // num-row index, mult of 4
    int b = r0 / P_;
    int t0 = r0 - b * P_;                  // mult of 4; 4 rows share b
    int e0 = lane * 4;
    float4 x4 = *(const float4*)&x_num[b * P_ + t0];   // broadcast, 16B-aligned
    float xs[4] = {x4.x, x4.y, x4.z, x4.w};
    const __half2* bases[4];
    float tts[4];
    #pragma unroll
    for (int j = 0; j < 4; ++j) {
        float s = (xs[j] - X0_) * INVDX_;
        float fi = floorf(s);
        fi = fminf(fmaxf(fi, 0.0f), (float)(NI_ - 1));
        tts[j] = s - fi;                   // unclamped -> linear extrapolation
        bases[j] = T2 + ((size_t)(t0 + j) * NI_ + (int)fi) * E_ + e0;
    }
    float4 raw[4];
    #pragma unroll
    for (int j = 0; j < 4; ++j)            // 4 independent 16B loads in flight
        raw[j] = *(const float4*)bases[j];
    int orow = b * TOK_ + t0;
    #pragma unroll
    for (int j = 0; j < 4; ++j) {
        const __half2* hp = (const __half2*)&raw[j];
        float2 p0 = __half22float2(hp[0]);
        float2 p1 = __half22float2(hp[1]);
        float2 p2 = __half22float2(hp[2]);
        float2 p3 = __half22float2(hp[3]);
        float4 v;
        v.x = fmaf(tts[j], p0.y, p0.x);
        v.y = fmaf(tts[j], p1.y, p1.x);
        v.z = fmaf(tts[j], p2.y, p2.x);
        v.w = fmaf(tts[j], p3.y, p3.x);
        ln_store(v, g, bt, e0, orow + j, out);
    }
}

// K1: blocks [0,384) build the packed table; blocks [384,384+6144) do all cat
// tokens q-major. Independent halves overlap; cat hides build latency.
__global__ __launch_bounds__(256) void build_and_cat(
        const float* __restrict__ W1, const float* __restrict__ b1,
        const float* __restrict__ W2, const float* __restrict__ b2,
        const int* __restrict__ x_cat, const float* __restrict__ emb,
        const float* __restrict__ gamma, const float* __restrict__ beta,
        __half2* __restrict__ T2, float* __restrict__ out) {
    __shared__ float h[KT_ + 1][E_ + 4];
    if (blockIdx.x < NBUILD_) {
        do_build_chunk(blockIdx.x, W1, b1, W2, b2, T2, h);
    } else {
        int wv = threadIdx.x >> 6;
        int lane = threadIdx.x & 63;
        int e0 = lane * 4;
        float4 g = *(const float4*)&gamma[e0];
        float4 bt = *(const float4*)&beta[e0];
        do_cat_tile(blockIdx.x - NBUILD_, wv, lane, x_cat, emb, g, bt, out);
    }
}

// K2: all numeric tokens via packed-table interpolation (table L2-hot, 1.6 MB).
__global__ __launch_bounds__(256) void fuse_num(
        const __half2* __restrict__ T2, const float* __restrict__ x_num,
        const float* __restrict__ gamma, const float* __restrict__ beta,
        float* __restrict__ out) {
    int wv = threadIdx.x >> 6;
    int lane = threadIdx.x & 63;
    int e0 = lane * 4;
    float4 g = *(const float4*)&gamma[e0];
    float4 bt = *(const float4*)&beta[e0];
    do_num_tile(blockIdx.x, wv, lane, T2, x_num, g, bt, out);
}

// Exact fallback (no workspace): direct per-row matvec with 64-lane LN.
__global__ __launch_bounds__(256) void fuse_exact(
        const float* __restrict__ x_num, const int* __restrict__ x_cat,
        const float* __restrict__ W1, const float* __restrict__ b1,
        const float* __restrict__ W2, const float* __restrict__ b2,
        const float* __restrict__ emb,
        const float* __restrict__ gamma, const float* __restrict__ beta,
        float* __restrict__ out) {
    int wv = threadIdx.x >> 6;
    int lane = threadIdx.x & 63;
    int row = blockIdx.x * 4 + wv;
    if (row >= B_ * TOK_) return;
    int b = row / TOK_;
    int t = row - b * TOK_;
    int e0 = lane * 4;
    float4 g = *(const float4*)&gamma[e0];
    float4 bt = *(const float4*)&beta[e0];
    float4 v;
    if (t < P_) {
        float x = x_num[b * P_ + t];
        float4 acc = *(const float4*)&b2[t * E_ + e0];
        for (int e = 0; e < E_; ++e) {
            float he = gelu_exact(fmaf(x, W1[t * E_ + e], b1[t * E_ + e]));
            float4 w = *(const float4*)&W2[((size_t)t * E_ + e) * E_ + e0];
            acc.x = fmaf(he, w.x, acc.x);
            acc.y = fmaf(he, w.y, acc.y);
            acc.z = fmaf(he, w.z, acc.z);
            acc.w = fmaf(he, w.w, acc.w);
        }
        v = acc;
    } else {
        int q = t - P_;
        int idx = x_cat[b * Q_ + q];
        v = *(const float4*)&emb[((size_t)q * V_ + idx) * E_ + e0];
    }
    ln_store(v, g, bt, e0, row, out);
}

extern "C" void kernel_launch(void* const* d_in, const int* in_sizes, int n_in,
                              void* d_out, int out_size, void* d_ws, size_t ws_size,
                              hipStream_t stream) {
    const float* x_num = (const float*)d_in[0];
    const int*   x_cat = (const int*)d_in[1];
    const float* W1    = (const float*)d_in[2];
    const float* b1    = (const float*)d_in[3];
    const float* W2    = (const float*)d_in[4];
    const float* b2    = (const float*)d_in[5];
    const float* emb   = (const float*)d_in[6];
    const float* gamma = (const float*)d_in[7];
    const float* beta  = (const float*)d_in[8];
    float* out = (float*)d_out;

    size_t tbl_bytes = (size_t)P_ * NI_ * E_ * sizeof(__half2);   // 1.6 MB

    if (ws_size >= tbl_bytes) {
        __half2* T2 = (__half2*)d_ws;
        build_and_cat<<<NBUILD_ + NCAT_TILES_, 256, 0, stream>>>(
            W1, b1, W2, b2, x_cat, emb, gamma, beta, T2, out);
        fuse_num<<<NNUM_TILES_, 256, 0, stream>>>(T2, x_num, gamma, beta, out);
    } else {
        int nrow_blocks = (B_ * TOK_ + 3) / 4;
        fuse_exact<<<nrow_blocks, 256, 0, stream>>>(x_num, x_cat, W1, b1, W2, b2,
                                                    emb, gamma, beta, out);
    }
}